// Round 1
// baseline (395.465 us; speedup 1.0000x reference)
//
#include <hip/hip_runtime.h>

#define N_NODES 8192
#define IN_F 256
#define OUT_F 32

using short8  = __attribute__((ext_vector_type(8))) short;
using floatx4 = __attribute__((ext_vector_type(4))) float;

// truncate fp32 -> bf16 (exact for adj values 0.0 / 1.0)
__device__ __forceinline__ short bf_trunc(float x) {
    return (short)(__float_as_uint(x) >> 16);
}

// ---------------------------------------------------------------------------
// Kernel 1: HW = h @ W  (fp32), store HW^T as bf16 (RNE) into ws: Bt[32][8192]
// grid: 1024 blocks x 256 threads; thread (j = blk*8 + tid/32, c = tid%32)
// ---------------------------------------------------------------------------
__global__ __launch_bounds__(256) void hw_kernel(const float* __restrict__ h,
                                                 const float* __restrict__ W,
                                                 unsigned short* __restrict__ Bt) {
    __shared__ float Wl[IN_F * OUT_F];  // 32 KB
    const int tid = threadIdx.x;
    for (int i = tid; i < IN_F * OUT_F; i += 256) Wl[i] = W[i];
    __syncthreads();

    const int j = blockIdx.x * 8 + (tid >> 5);
    const int c = tid & 31;
    const float* hrow = h + (long)j * IN_F;

    float acc = 0.f;
    #pragma unroll 4
    for (int k = 0; k < IN_F; k += 4) {
        const float4 h4 = *(const float4*)(hrow + k);
        acc += h4.x * Wl[(k + 0) * 32 + c];
        acc += h4.y * Wl[(k + 1) * 32 + c];
        acc += h4.z * Wl[(k + 2) * 32 + c];
        acc += h4.w * Wl[(k + 3) * 32 + c];
    }
    // round-to-nearest-even fp32 -> bf16
    unsigned u = __float_as_uint(acc);
    u += 0x7fffu + ((u >> 16) & 1u);
    Bt[(long)c * N_NODES + j] = (unsigned short)(u >> 16);
}

// ---------------------------------------------------------------------------
// Kernel 2: out[8192][32] = adj[8192][8192] @ HW[8192][32]
// MFMA bf16 16x16x32. Block = 256 thr = 4 waves; block owns 16 output rows;
// waves split K (2048 each); LDS reduce at end. 512 blocks.
// A-frag: A[m=lane&15][k = (lane>>4)*8 + j]
// B-frag: B[k = (lane>>4)*8 + j][n = lane&15]   (Bt[n][k] contiguous in k)
// D:      row = (lane>>4)*4 + reg, col = lane&15
// ---------------------------------------------------------------------------
__global__ __launch_bounds__(256) void spmm_kernel(const float* __restrict__ adj,
                                                   const unsigned short* __restrict__ Bt,
                                                   float* __restrict__ out) {
    const int tid  = threadIdx.x;
    const int wave = tid >> 6;
    const int lane = tid & 63;
    const int m    = lane & 15;
    const int q    = lane >> 4;
    const int m0   = blockIdx.x * 16;
    const long kw  = (long)wave * 2048;

    const float*          arow = adj + (long)(m0 + m) * N_NODES + kw + q * 8;
    const unsigned short* b0p  = Bt + (long)m * N_NODES + kw + q * 8;
    const unsigned short* b1p  = b0p + 16L * N_NODES;

    floatx4 acc0 = {0.f, 0.f, 0.f, 0.f};
    floatx4 acc1 = {0.f, 0.f, 0.f, 0.f};

    #pragma unroll 2
    for (int ks = 0; ks < 64; ++ks) {
        const float4 a0 = *(const float4*)(arow);
        const float4 a1 = *(const float4*)(arow + 4);
        short8 afrag;
        afrag[0] = bf_trunc(a0.x);
        afrag[1] = bf_trunc(a0.y);
        afrag[2] = bf_trunc(a0.z);
        afrag[3] = bf_trunc(a0.w);
        afrag[4] = bf_trunc(a1.x);
        afrag[5] = bf_trunc(a1.y);
        afrag[6] = bf_trunc(a1.z);
        afrag[7] = bf_trunc(a1.w);

        const short8 bfrag0 = *(const short8*)(b0p);
        const short8 bfrag1 = *(const short8*)(b1p);

        acc0 = __builtin_amdgcn_mfma_f32_16x16x32_bf16(afrag, bfrag0, acc0, 0, 0, 0);
        acc1 = __builtin_amdgcn_mfma_f32_16x16x32_bf16(afrag, bfrag1, acc1, 0, 0, 0);

        arow += 32;
        b0p  += 32;
        b1p  += 32;
    }

    __shared__ float red[4][16][32];  // 8 KB
    #pragma unroll
    for (int r = 0; r < 4; ++r) {
        red[wave][q * 4 + r][m]      = acc0[r];
        red[wave][q * 4 + r][16 + m] = acc1[r];
    }
    __syncthreads();

    for (int e = tid; e < 16 * 32; e += 256) {
        const int mm = e >> 5;
        const int nn = e & 31;
        const float s = red[0][mm][nn] + red[1][mm][nn] +
                        red[2][mm][nn] + red[3][mm][nn];
        out[(long)(m0 + mm) * OUT_F + nn] = s;
    }
}

// ---------------------------------------------------------------------------
extern "C" void kernel_launch(void* const* d_in, const int* in_sizes, int n_in,
                              void* d_out, int out_size, void* d_ws, size_t ws_size,
                              hipStream_t stream) {
    const float* h   = (const float*)d_in[0];   // [8192][256]
    const float* adj = (const float*)d_in[1];   // [8192][8192]
    const float* W   = (const float*)d_in[2];   // [256][32]
    float* out = (float*)d_out;                 // [8192][32]
    unsigned short* Bt = (unsigned short*)d_ws; // [32][8192] bf16, 512 KB

    hw_kernel<<<N_NODES / 8, 256, 0, stream>>>(h, W, Bt);
    spmm_kernel<<<N_NODES / 16, 256, 0, stream>>>(adj, Bt, out);
}

// Round 3
// 392.766 us; speedup vs baseline: 1.0069x; 1.0069x over previous
//
#include <hip/hip_runtime.h>

#define N_NODES 8192
#define IN_F 256
#define OUT_F 32

using short8  = __attribute__((ext_vector_type(8))) short;
using floatx4 = __attribute__((ext_vector_type(4))) float;

// truncate fp32 -> bf16 (exact for adj values 0.0 / 1.0)
__device__ __forceinline__ short bf_trunc(float x) {
    return (short)(__float_as_uint(x) >> 16);
}

// ---------------------------------------------------------------------------
// Kernel 1: HW = h @ W  (fp32), store HW^T as bf16 (RNE) into ws: Bt[32][8192]
// grid: 1024 blocks x 256 threads; thread (j = blk*8 + tid/32, c = tid%32)
// ---------------------------------------------------------------------------
__global__ __launch_bounds__(256) void hw_kernel(const float* __restrict__ h,
                                                 const float* __restrict__ W,
                                                 unsigned short* __restrict__ Bt) {
    __shared__ float Wl[IN_F * OUT_F];  // 32 KB
    const int tid = threadIdx.x;
    for (int i = tid; i < IN_F * OUT_F; i += 256) Wl[i] = W[i];
    __syncthreads();

    const int j = blockIdx.x * 8 + (tid >> 5);
    const int c = tid & 31;
    const float* hrow = h + (long)j * IN_F;

    float acc = 0.f;
    #pragma unroll 4
    for (int k = 0; k < IN_F; k += 4) {
        const float4 h4 = *(const float4*)(hrow + k);
        acc += h4.x * Wl[(k + 0) * 32 + c];
        acc += h4.y * Wl[(k + 1) * 32 + c];
        acc += h4.z * Wl[(k + 2) * 32 + c];
        acc += h4.w * Wl[(k + 3) * 32 + c];
    }
    // round-to-nearest-even fp32 -> bf16
    unsigned u = __float_as_uint(acc);
    u += 0x7fffu + ((u >> 16) & 1u);
    Bt[(long)c * N_NODES + j] = (unsigned short)(u >> 16);
}

// ---------------------------------------------------------------------------
// Kernel 2: out[8192][32] = adj[8192][8192] @ HW[8192][32]
// MFMA bf16 16x16x32. Block = 512 thr = 8 waves; block owns 16 output rows;
// waves split K (1024 each); LDS reduce at end. 512 blocks -> 16 waves/CU.
// A-frag: A[m=lane&15][k = (lane>>4)*8 + j]
// B-frag: B[k = (lane>>4)*8 + j][n = lane&15]   (Bt[n][k] contiguous in k)
// D:      row = (lane>>4)*4 + reg, col = lane&15
// ---------------------------------------------------------------------------
__global__ __launch_bounds__(512) void spmm_kernel(const float* __restrict__ adj,
                                                   const unsigned short* __restrict__ Bt,
                                                   float* __restrict__ out) {
    const int tid  = threadIdx.x;
    const int wave = tid >> 6;   // 0..7
    const int lane = tid & 63;
    const int m    = lane & 15;
    const int q    = lane >> 4;
    const int m0   = blockIdx.x * 16;
    const long kw  = (long)wave * 1024;

    const float*          arow = adj + (long)(m0 + m) * N_NODES + kw + q * 8;
    const unsigned short* b0p  = Bt + (long)m * N_NODES + kw + q * 8;
    const unsigned short* b1p  = b0p + 16L * N_NODES;

    floatx4 acc0 = {0.f, 0.f, 0.f, 0.f};
    floatx4 acc1 = {0.f, 0.f, 0.f, 0.f};

    #pragma unroll 4
    for (int ks = 0; ks < 32; ++ks) {
        // non-temporal: adj is streamed once; keep Bt resident in L2
        const floatx4 a0 = __builtin_nontemporal_load((const floatx4*)(arow));
        const floatx4 a1 = __builtin_nontemporal_load((const floatx4*)(arow) + 1);
        short8 afrag;
        afrag[0] = bf_trunc(a0[0]);
        afrag[1] = bf_trunc(a0[1]);
        afrag[2] = bf_trunc(a0[2]);
        afrag[3] = bf_trunc(a0[3]);
        afrag[4] = bf_trunc(a1[0]);
        afrag[5] = bf_trunc(a1[1]);
        afrag[6] = bf_trunc(a1[2]);
        afrag[7] = bf_trunc(a1[3]);

        const short8 bfrag0 = *(const short8*)(b0p);
        const short8 bfrag1 = *(const short8*)(b1p);

        acc0 = __builtin_amdgcn_mfma_f32_16x16x32_bf16(afrag, bfrag0, acc0, 0, 0, 0);
        acc1 = __builtin_amdgcn_mfma_f32_16x16x32_bf16(afrag, bfrag1, acc1, 0, 0, 0);

        arow += 32;
        b0p  += 32;
        b1p  += 32;
    }

    __shared__ float red[8][16][32];  // 16 KB
    #pragma unroll
    for (int r = 0; r < 4; ++r) {
        red[wave][q * 4 + r][m]      = acc0[r];
        red[wave][q * 4 + r][16 + m] = acc1[r];
    }
    __syncthreads();

    // one element per thread: 512 threads == 16*32 outputs
    {
        const int mm = tid >> 5;
        const int nn = tid & 31;
        float s = 0.f;
        #pragma unroll
        for (int w = 0; w < 8; ++w) s += red[w][mm][nn];
        out[(long)(m0 + mm) * OUT_F + nn] = s;
    }
}

// ---------------------------------------------------------------------------
extern "C" void kernel_launch(void* const* d_in, const int* in_sizes, int n_in,
                              void* d_out, int out_size, void* d_ws, size_t ws_size,
                              hipStream_t stream) {
    const float* h   = (const float*)d_in[0];   // [8192][256]
    const float* adj = (const float*)d_in[1];   // [8192][8192]
    const float* W   = (const float*)d_in[2];   // [256][32]
    float* out = (float*)d_out;                 // [8192][32]
    unsigned short* Bt = (unsigned short*)d_ws; // [32][8192] bf16, 512 KB

    hw_kernel<<<N_NODES / 8, 256, 0, stream>>>(h, W, Bt);
    spmm_kernel<<<N_NODES / 16, 512, 0, stream>>>(adj, Bt, out);
}